// Round 6
// baseline (387.707 us; speedup 1.0000x reference)
//
#include <hip/hip_runtime.h>
#include <cfloat>
#include <climits>

// Problem constants
#define N_ROWS 65536          // 64*1024 flattened rows
#define DIM 256
#define K_CODES 1024
#define N_ELEM 16777216       // N_ROWS*DIM
#define OUT_LOSS_OFF 16777216
#define OUT_IDX_OFF  16777217

#define ROWS_PB 128           // rows per block (argmin)
#define CT 128                // codes per tile
// Ref dists are fp32 with +||x||^2 (~256): grid ulp 3.05e-5, flip band ~6.6e-5.
// Pass-1 is now plain bf16 MFMA: err sigma ~2.8e-5/code (x_lo*e + x*e_lo dropped).
// Margin 3.5e-4 = flip band + ~7 sigma of err-diff. Flag rate ~4.5%.
#define EPS_MARGIN 3.5e-4f
#define SHORTLIST_EPS 6e-4f   // covers phase-A err (~1.2e-4 @6sigma) + flip band
#define RB 8                  // flagged rows batched per rescore block

// ws layout (bytes)
#define WS_PARTIALS 0         // 1024 double
#define WS_ESQ      8192      // 1024 float
#define WS_IDX      12288     // 65536 int
#define WS_FLAGCNT  274432    // 1 int
#define WS_FLAGLIST 274436    // up to 65536 int -> ends 536580
#define WS_EHI      540672    // 1024*256 u16 = 512 KB row-major bf16 (argmin B)
#define WS_EHIT     1064960   // 512 KB q-major transpose (rescore) -> ends 1589248

typedef unsigned short u16;
typedef __attribute__((ext_vector_type(8))) short bf16x8;
typedef __attribute__((ext_vector_type(4))) float f32x4;

// ---- fp32 -> bf16 RN ----
__device__ __forceinline__ u16 bf16rn(float f) {
    unsigned u = __float_as_uint(f);
    return (u16)((u + 0x7fffu + ((u >> 16) & 1u)) >> 16);
}
__device__ __forceinline__ unsigned pack2(float a, float b) {
    return (unsigned)bf16rn(a) | ((unsigned)bf16rn(b) << 16);
}

// ---- numpy fp32 pairwise sum-of-squares over 256 elements (round-3 proven) ----
__device__ __forceinline__ float np_pairwise_sumsq(const float* __restrict__ a) {
    float half[2];
    #pragma unroll
    for (int h = 0; h < 2; ++h) {
        const float* p = a + h * 128;
        float r[8];
        #pragma unroll
        for (int j = 0; j < 8; ++j) r[j] = __fmul_rn(p[j], p[j]);
        for (int i = 8; i < 128; i += 8) {
            #pragma unroll
            for (int j = 0; j < 8; ++j)
                r[j] = __fadd_rn(r[j], __fmul_rn(p[i + j], p[i + j]));
        }
        half[h] = __fadd_rn(__fadd_rn(__fadd_rn(r[0], r[1]), __fadd_rn(r[2], r[3])),
                            __fadd_rn(__fadd_rn(r[4], r[5]), __fadd_rn(r[6], r[7])));
    }
    return __fadd_rn(half[0], half[1]);
}

// ---------------- prep: e -> bf16 row-major + q-major transpose ----------------
__global__ void eprep_kernel(const float* __restrict__ e, u16* __restrict__ ehi,
                             u16* __restrict__ ehiT) {
    int i4 = blockIdx.x * 256 + threadIdx.x;       // 0..65535 float4 units
    float4 v = ((const float4*)e)[i4];
    ushort4 h;
    h.x = bf16rn(v.x); h.y = bf16rn(v.y); h.z = bf16rn(v.z); h.w = bf16rn(v.w);
    ((ushort4*)ehi)[i4] = h;
    int c = i4 >> 6;
    int f4 = i4 & 63;
    int qid = f4 >> 1;
    ((ushort4*)ehiT)[((size_t)qid * 1024 + c) * 2 + (f4 & 1)] = h;
}

// ---------------- per-code squared norms (numpy-order fp32, round-3 proven) ----
__global__ void esq_kernel(const float* __restrict__ e, float* __restrict__ esq) {
    int c = blockIdx.x * 256 + threadIdx.x;
    if (c < K_CODES) esq[c] = np_pairwise_sumsq(e + c * DIM);
}

// ---------------- Kernel A: bf16 MFMA distance + argmin, barrier-free K-loop --
// Block: 128 rows x all 1024 codes; 4 waves 2x2, each 64 rows x 64 codes.
// x: fp32->bf16 in-kernel, staged full-dim in LDS ONCE ([ch][128][64] u16,
// 16B-blocks XOR-swizzled by row&7 -> 2-way conflicts only = free).
// e: B-fragments loaded DIRECTLY from global ehi (L2-resident 0.5 MB) -> no
// e staging, no per-tile barriers; MFMA<->vmem pipelined by compiler vmcnt.
__launch_bounds__(256, 2)
__global__ void argmin_kernel(const float* __restrict__ x, const u16* __restrict__ ehi,
                              const float* __restrict__ esq, int* __restrict__ wsIdx,
                              int* __restrict__ flagCnt, int* __restrict__ flagList) {
    __shared__ __align__(16) unsigned char lds[65536];
    u16* xS = (u16*)lds;                  // [4 ch][128 r][64] swizzled

    const int t = threadIdx.x;
    const int w = t >> 6;                 // wave 0..3
    const int l = t & 63;
    const int lane15 = l & 15;
    const int quad = l >> 4;              // 0..3
    const int rowBase = blockIdx.x * ROWS_PB;
    const int waveRowOff = (w >> 1) * 64;
    const int waveColOff = (w & 1) * 64;

    // ---- stage x once: 16 units/thread, unit = 8 elems ----
    #pragma unroll
    for (int q = 0; q < 16; ++q) {
        int id = q * 256 + t;             // 0..4095
        int jb = id & 7;                  // 16B block within 64-d chunk
        int r = (id >> 3) & 127;
        int ch = id >> 10;                // 0..3
        const float4* g = (const float4*)(x + (size_t)(rowBase + r) * 256 + ch * 64 + jb * 8);
        float4 a = g[0], b = g[1];
        uint4 p;
        p.x = pack2(a.x, a.y); p.y = pack2(a.z, a.w);
        p.z = pack2(b.x, b.y); p.w = pack2(b.z, b.w);
        *(uint4*)(void*)(xS + ch * 8192 + r * 64 + ((jb ^ (r & 7)) * 8)) = p;
    }
    __syncthreads();

    float bv[16], sv[16]; int bi[16];
    #pragma unroll
    for (int i = 0; i < 16; ++i) { bv[i] = FLT_MAX; sv[i] = FLT_MAX; bi[i] = INT_MAX; }

    // per-lane constants
    const u16* bbase[4];
    #pragma unroll
    for (int tj = 0; tj < 4; ++tj)
        bbase[tj] = ehi + (size_t)(waveColOff + tj * 16 + lane15) * 256 + quad * 8;
    int rbase[4], rx[4];
    #pragma unroll
    for (int ti = 0; ti < 4; ++ti) {
        int r = waveRowOff + ti * 16 + lane15;
        rbase[ti] = r * 64; rx[ti] = r & 7;
    }

    #pragma unroll 1
    for (int ct = 0; ct < 8; ++ct) {
        const int ctBase = ct * CT;
        f32x4 acc[4][4];
        #pragma unroll
        for (int ti = 0; ti < 4; ++ti)
            #pragma unroll
            for (int tj = 0; tj < 4; ++tj) acc[ti][tj] = (f32x4){0.f, 0.f, 0.f, 0.f};

        #pragma unroll
        for (int ks = 0; ks < 8; ++ks) {          // k0 = ks*32
            bf16x8 af[4], bfv[4];
            #pragma unroll
            for (int tj = 0; tj < 4; ++tj)        // global (L2) B-frags
                bfv[tj] = *(const bf16x8*)(bbase[tj] + ctBase * 256 + ks * 32);
            #pragma unroll
            for (int ti = 0; ti < 4; ++ti) {      // LDS A-frags (swizzled)
                int off = (ks >> 1) * 8192 + rbase[ti]
                        + ((((ks & 1) * 4 + quad) ^ rx[ti]) * 8);
                af[ti] = *(const bf16x8*)(xS + off);
            }
            #pragma unroll
            for (int ti = 0; ti < 4; ++ti)
                #pragma unroll
                for (int tj = 0; tj < 4; ++tj)
                    acc[ti][tj] = __builtin_amdgcn_mfma_f32_16x16x32_bf16(
                        af[ti], bfv[tj], acc[ti][tj], 0, 0, 0);
        }

        // epilogue: s = ||e||^2 - 2*dot. D-layout: row(M)=quad*4+reg, col(N)=lane&15
        // (proven rounds 4-5). Candidates ascend in c -> '<' keeps lowest index.
        #pragma unroll
        for (int tj = 0; tj < 4; ++tj) {
            int cLoc = waveColOff + tj * 16 + lane15;
            float cs = esq[ctBase + cLoc];
            int c = ctBase + cLoc;
            #pragma unroll
            for (int ti = 0; ti < 4; ++ti)
                #pragma unroll
                for (int r4 = 0; r4 < 4; ++r4) {
                    int slot = ti * 4 + r4;
                    float s = fmaf(-2.0f, acc[ti][tj][r4], cs);
                    if (s < bv[slot]) {
                        sv[slot] = bv[slot]; bv[slot] = s; bi[slot] = c;
                    } else if (s < sv[slot]) {
                        sv[slot] = s;
                    }
                }
        }
    }

    // ---- final cross-contributor top-2 merge via LDS (reuses xS; proven r4-5) --
    __syncthreads();
    float* bvA = (float*)lds;                     // [128 rows][32 contributors]
    float* svA = (float*)(lds + 16384);
    int*   biA = (int*)(lds + 32768);
    const int contrib = (w & 1) * 16 + lane15;    // 0..31
    #pragma unroll
    for (int slot = 0; slot < 16; ++slot) {
        int m = waveRowOff + (slot >> 2) * 16 + quad * 4 + (slot & 3);
        bvA[m * 32 + contrib] = bv[slot];
        svA[m * 32 + contrib] = sv[slot];
        biA[m * 32 + contrib] = bi[slot];
    }
    __syncthreads();

    if (t < ROWS_PB) {
        float bb = FLT_MAX, ss = FLT_MAX;
        int ii = INT_MAX;
        for (int k = 0; k < 32; ++k) {
            float v  = bvA[t * 32 + k];
            int   id = biA[t * 32 + k];
            float s2 = svA[t * 32 + k];
            if (v < bb || (v == bb && id < ii)) {
                ss = fminf(bb, s2);
                bb = v; ii = id;
            } else {
                ss = fminf(ss, v);
            }
        }
        int row = rowBase + t;
        wsIdx[row] = ii;
        if (ss - bb < EPS_MARGIN) {
            int p = atomicAdd(flagCnt, 1);
            flagList[p] = row;
        }
    }
}

// ------- Kernel A2: flagged-row rescore, RB rows batched per block (r5 proven) --
// Phase A: bf16-hi fp32 scores over all 1024 codes via q-major ehiT (coalesced,
// shared across 8 rows) -> per-row shortlist within SHORTLIST_EPS of min.
// Phase B: numpy-emulated quantized score on shortlist; (s, idx) argmin.
__launch_bounds__(256)
__global__ void rescore_kernel(const float* __restrict__ x, const float* __restrict__ e,
                               const u16* __restrict__ ehiT, const float* __restrict__ esq,
                               int* __restrict__ wsIdx, const int* __restrict__ flagCnt,
                               const int* __restrict__ flagList) {
    __shared__ __align__(16) float xsh[RB][DIM];
    __shared__ float Ash[RB];
    __shared__ float minsh[RB][256];
    __shared__ float thrsh[RB];
    __shared__ int scnt[RB];
    __shared__ int slist[RB][32];
    __shared__ float sres[RB][32];
    const int t = threadIdx.x;
    const int cnt = *flagCnt;
    const int ngroups = (cnt + RB - 1) / RB;
    for (int g = blockIdx.x; g < ngroups; g += gridDim.x) {
        const int base = g * RB;
        const int nr = (cnt - base < RB) ? (cnt - base) : RB;
        __syncthreads();
        #pragma unroll
        for (int r = 0; r < RB; ++r)
            xsh[r][t] = (r < nr) ? x[(size_t)flagList[base + r] * DIM + t] : 0.0f;
        if (t < RB) scnt[t] = 0;
        __syncthreads();
        if (t < RB) Ash[t] = np_pairwise_sumsq(xsh[t]);

        float sA[4][RB];
        #pragma unroll
        for (int j = 0; j < 4; ++j)
            #pragma unroll
            for (int r = 0; r < RB; ++r) sA[j][r] = 0.0f;

        const uint4* eT4 = (const uint4*)ehiT;
        for (int q = 0; q < 32; ++q) {
            float4 xq[RB][2];
            #pragma unroll
            for (int r = 0; r < RB; ++r) {
                xq[r][0] = ((const float4*)xsh[r])[2 * q];
                xq[r][1] = ((const float4*)xsh[r])[2 * q + 1];
            }
            #pragma unroll
            for (int j = 0; j < 4; ++j) {
                uint4 uv = eT4[(size_t)q * 1024 + j * 256 + t];
                float e0 = __uint_as_float(uv.x << 16);
                float e1 = __uint_as_float(uv.x & 0xffff0000u);
                float e2 = __uint_as_float(uv.y << 16);
                float e3 = __uint_as_float(uv.y & 0xffff0000u);
                float e4v = __uint_as_float(uv.z << 16);
                float e5 = __uint_as_float(uv.z & 0xffff0000u);
                float e6 = __uint_as_float(uv.w << 16);
                float e7 = __uint_as_float(uv.w & 0xffff0000u);
                #pragma unroll
                for (int r = 0; r < RB; ++r) {
                    float d0 = sA[j][r];
                    d0 = fmaf(e0, xq[r][0].x, d0);
                    d0 = fmaf(e1, xq[r][0].y, d0);
                    d0 = fmaf(e2, xq[r][0].z, d0);
                    d0 = fmaf(e3, xq[r][0].w, d0);
                    d0 = fmaf(e4v, xq[r][1].x, d0);
                    d0 = fmaf(e5, xq[r][1].y, d0);
                    d0 = fmaf(e6, xq[r][1].z, d0);
                    d0 = fmaf(e7, xq[r][1].w, d0);
                    sA[j][r] = d0;
                }
            }
        }
        #pragma unroll
        for (int j = 0; j < 4; ++j) {
            float cs = esq[j * 256 + t];
            #pragma unroll
            for (int r = 0; r < RB; ++r)
                sA[j][r] = fmaf(-2.0f, sA[j][r], cs);
        }
        #pragma unroll
        for (int r = 0; r < RB; ++r)
            minsh[r][t] = fminf(fminf(sA[0][r], sA[1][r]), fminf(sA[2][r], sA[3][r]));
        __syncthreads();
        for (int off = 128; off > 0; off >>= 1) {
            if (t < off) {
                #pragma unroll
                for (int r = 0; r < RB; ++r)
                    minsh[r][t] = fminf(minsh[r][t], minsh[r][t + off]);
            }
            __syncthreads();
        }
        if (t < RB) thrsh[t] = minsh[t][0] + SHORTLIST_EPS;
        __syncthreads();
        #pragma unroll
        for (int j = 0; j < 4; ++j)
            #pragma unroll
            for (int r = 0; r < RB; ++r)
                if (r < nr && sA[j][r] <= thrsh[r]) {
                    int p = atomicAdd(&scnt[r], 1);
                    if (p < 32) slist[r][p] = j * 256 + t;
                }
        __syncthreads();
        {
            int r = t >> 5, k = t & 31;
            int ns = scnt[r] < 32 ? scnt[r] : 32;
            if (r < nr && k < ns) {
                int c = slist[r][k];
                const float4* ec4 = (const float4*)(e + (size_t)c * DIM);
                const float4* xc4 = (const float4*)xsh[r];
                double dot = 0.0;
                #pragma unroll 8
                for (int d4 = 0; d4 < 64; ++d4) {
                    float4 ev = ec4[d4];
                    float4 xv = xc4[d4];
                    dot += (double)ev.x * (double)xv.x + (double)ev.y * (double)xv.y
                         + (double)ev.z * (double)xv.z + (double)ev.w * (double)xv.w;
                }
                float M = (float)dot;
                sres[r][k] = __fsub_rn(__fadd_rn(Ash[r], esq[c]), __fmul_rn(2.0f, M));
            }
        }
        __syncthreads();
        if (t < nr) {
            int ns = scnt[t] < 32 ? scnt[t] : 32;
            float bb = FLT_MAX; int ii = INT_MAX;
            for (int k = 0; k < ns; ++k) {
                float s = sres[t][k]; int c = slist[t][k];
                if (s < bb || (s == bb && c < ii)) { bb = s; ii = c; }
            }
            wsIdx[flagList[base + t]] = ii;
        }
    }
}

// ---------------- Kernel B: gather quantized + SSE partials + indices-as-float --
__global__ void gather_kernel(const float* __restrict__ x, const float* __restrict__ e,
                              const int* __restrict__ wsIdx, float* __restrict__ out,
                              double* __restrict__ partials) {
    const float4* x4 = (const float4*)x;
    const float4* e4 = (const float4*)e;
    float4* q4 = (float4*)out;
    float* outIdx = out + OUT_IDX_OFF;
    const int tid = blockIdx.x * 256 + threadIdx.x;   // 0..262143
    double sse = 0.0;
    #pragma unroll 4
    for (int i = 0; i < 16; ++i) {
        int u = tid + i * 262144;      // float4 unit, 0..4194303
        int row = u >> 6;
        int c4 = u & 63;
        int idx = wsIdx[row];
        float4 q = e4[idx * 64 + c4];
        float4 xv = x4[u];
        q4[u] = q;
        double dx = (double)q.x - (double)xv.x;
        double dy = (double)q.y - (double)xv.y;
        double dz = (double)q.z - (double)xv.z;
        double dw = (double)q.w - (double)xv.w;
        sse += dx * dx + dy * dy + dz * dz + dw * dw;
    }
    if (tid < N_ROWS) outIdx[tid] = (float)wsIdx[tid];
    #pragma unroll
    for (int m = 1; m < 64; m <<= 1) sse += __shfl_xor(sse, m);
    __shared__ double wsum[4];
    if ((threadIdx.x & 63) == 0) wsum[threadIdx.x >> 6] = sse;
    __syncthreads();
    if (threadIdx.x == 0)
        partials[blockIdx.x] = wsum[0] + wsum[1] + wsum[2] + wsum[3];
}

// ---------------- Kernel C: final loss reduce ----------------
__global__ void loss_kernel(const double* __restrict__ partials, float* __restrict__ out) {
    __shared__ double sh[256];
    const int t = threadIdx.x;
    double s = partials[t] + partials[t + 256] + partials[t + 512] + partials[t + 768];
    sh[t] = s;
    __syncthreads();
    for (int off = 128; off > 0; off >>= 1) {
        if (t < off) sh[t] += sh[t + off];
        __syncthreads();
    }
    if (t == 0) out[OUT_LOSS_OFF] = (float)(0.25 * sh[0] / (double)N_ELEM);
}

extern "C" void kernel_launch(void* const* d_in, const int* in_sizes, int n_in,
                              void* d_out, int out_size, void* d_ws, size_t ws_size,
                              hipStream_t stream) {
    (void)in_sizes; (void)n_in; (void)out_size; (void)ws_size;
    const float* x = (const float*)d_in[0];
    const float* e = (const float*)d_in[1];
    float* out = (float*)d_out;
    char* ws = (char*)d_ws;
    double* partials = (double*)(ws + WS_PARTIALS);
    float* esq = (float*)(ws + WS_ESQ);
    int* wsIdx = (int*)(ws + WS_IDX);
    int* flagCnt = (int*)(ws + WS_FLAGCNT);
    int* flagList = (int*)(ws + WS_FLAGLIST);
    u16* ehi = (u16*)(ws + WS_EHI);
    u16* ehiT = (u16*)(ws + WS_EHIT);

    hipMemsetAsync(flagCnt, 0, sizeof(int), stream);
    eprep_kernel<<<256, 256, 0, stream>>>(e, ehi, ehiT);
    esq_kernel<<<4, 256, 0, stream>>>(e, esq);
    argmin_kernel<<<N_ROWS / ROWS_PB, 256, 0, stream>>>(x, ehi, esq, wsIdx,
                                                        flagCnt, flagList);
    rescore_kernel<<<512, 256, 0, stream>>>(x, e, ehiT, esq, wsIdx, flagCnt, flagList);
    gather_kernel<<<1024, 256, 0, stream>>>(x, e, wsIdx, out, partials);
    loss_kernel<<<1, 256, 0, stream>>>(partials, out);
}

// Round 7
// 385.595 us; speedup vs baseline: 1.0055x; 1.0055x over previous
//
#include <hip/hip_runtime.h>
#include <cfloat>
#include <climits>

// Problem constants
#define N_ROWS 65536          // 64*1024 flattened rows
#define DIM 256
#define K_CODES 1024
#define N_ELEM 16777216       // N_ROWS*DIM
#define OUT_LOSS_OFF 16777216
#define OUT_IDX_OFF  16777217

#define ROWS_PB 128           // rows per block (argmin)
#define CT 128                // codes per tile
// Ref dists are fp32 with +||x||^2 (~256): grid ulp 3.05e-5, flip band ~6.6e-5.
// Pass-1 is plain bf16 MFMA: err sigma ~2.8e-5/code. Margin 3.5e-4 = flip band
// + ~7 sigma. Validated round 6 (passed, absmax 3.8e-6). Do not change.
#define EPS_MARGIN 3.5e-4f
#define SHORTLIST_EPS 6e-4f
#define RB 8                  // flagged rows batched per rescore block

// ws layout (bytes)
#define WS_PARTIALS 0         // 512 double = 4096
#define WS_DELTA    4096      // 1 double
#define WS_FLAGCNT  4104      // 1 int (memset 16B covers delta+flagCnt)
#define WS_ESQ      8192      // 1024 float
#define WS_FLAGLIST 12288     // 65536 int -> ends 274432
#define WS_EHI      274432    // 512 KB row-major bf16 -> ends 798720
#define WS_EHIT     798720    // 512 KB q-major transpose -> ends 1310720

typedef unsigned short u16;
typedef __attribute__((ext_vector_type(8))) short bf16x8;
typedef __attribute__((ext_vector_type(4))) float f32x4;

// ---- async global->LDS 16B (wave-uniform LDS base + lane*16; r5-proven) ----
__device__ __forceinline__ void glds16(const u16* g, u16* l) {
    __builtin_amdgcn_global_load_lds(
        (const __attribute__((address_space(1))) unsigned int*)(const void*)g,
        (__attribute__((address_space(3))) unsigned int*)(void*)l,
        16, 0, 0);
}

// ---- fp32 -> bf16 RN ----
__device__ __forceinline__ u16 bf16rn(float f) {
    unsigned u = __float_as_uint(f);
    return (u16)((u + 0x7fffu + ((u >> 16) & 1u)) >> 16);
}
__device__ __forceinline__ unsigned pack2(float a, float b) {
    return (unsigned)bf16rn(a) | ((unsigned)bf16rn(b) << 16);
}

// ---- numpy fp32 pairwise sum-of-squares over 256 elements (round-3 proven) ----
__device__ __forceinline__ float np_pairwise_sumsq(const float* __restrict__ a) {
    float half[2];
    #pragma unroll
    for (int h = 0; h < 2; ++h) {
        const float* p = a + h * 128;
        float r[8];
        #pragma unroll
        for (int j = 0; j < 8; ++j) r[j] = __fmul_rn(p[j], p[j]);
        for (int i = 8; i < 128; i += 8) {
            #pragma unroll
            for (int j = 0; j < 8; ++j)
                r[j] = __fadd_rn(r[j], __fmul_rn(p[i + j], p[i + j]));
        }
        half[h] = __fadd_rn(__fadd_rn(__fadd_rn(r[0], r[1]), __fadd_rn(r[2], r[3])),
                            __fadd_rn(__fadd_rn(r[4], r[5]), __fadd_rn(r[6], r[7])));
    }
    return __fadd_rn(half[0], half[1]);
}

// -------- prep: e -> bf16 row-major + q-major transpose; fused esq ----------
__global__ void eprep_kernel(const float* __restrict__ e, u16* __restrict__ ehi,
                             u16* __restrict__ ehiT, float* __restrict__ esq) {
    int i4 = blockIdx.x * 256 + threadIdx.x;       // 0..65535 float4 units
    float4 v = ((const float4*)e)[i4];
    ushort4 h;
    h.x = bf16rn(v.x); h.y = bf16rn(v.y); h.z = bf16rn(v.z); h.w = bf16rn(v.w);
    ((ushort4*)ehi)[i4] = h;
    int c = i4 >> 6;
    int f4 = i4 & 63;
    int qid = f4 >> 1;
    ((ushort4*)ehiT)[((size_t)qid * 1024 + c) * 2 + (f4 & 1)] = h;
    if (blockIdx.x < 4) {
        int cc = blockIdx.x * 256 + threadIdx.x;
        esq[cc] = np_pairwise_sumsq(e + cc * DIM);
    }
}

// ---------------- Kernel A: bf16 MFMA argmin + fused gather/SSE ----------------
// Block: 128 rows x 1024 codes; 4 waves 2x2, each 64 rows x 64 codes.
// x: fp32->bf16 staged to LDS once, then A-frags pulled into 128 VGPRs/lane.
// e: [128 codes][64 d] tiles double-buffered in LDS via global_load_lds
// (coalesced), 32 MFMAs per barrier. Epilogue merges top-2, then the block
// gathers quantized output + fp64 SSE partial for its rows.
__launch_bounds__(256, 2)
__global__ void argmin_kernel(const float* __restrict__ x, const u16* __restrict__ ehi,
                              const float* __restrict__ esq, const float* __restrict__ e,
                              float* __restrict__ out, double* __restrict__ partials,
                              int* __restrict__ flagCnt, int* __restrict__ flagList) {
    __shared__ __align__(16) unsigned char lds[65536];
    u16* xS = (u16*)lds;                  // phase 0: [4 ch][128 r][64] swizzled

    const int t = threadIdx.x;
    const int w = t >> 6;                 // wave 0..3
    const int l = t & 63;
    const int lane15 = l & 15;
    const int quad = l >> 4;              // 0..3
    const int rowBase = blockIdx.x * ROWS_PB;
    const int waveRowOff = (w >> 1) * 64;
    const int waveColOff = (w & 1) * 64;

    // ---- phase 0: stage x once (fp32->bf16, swizzled; r6-proven) ----
    #pragma unroll
    for (int q = 0; q < 16; ++q) {
        int id = q * 256 + t;             // 0..4095
        int jb = id & 7;
        int r = (id >> 3) & 127;
        int ch = id >> 10;
        const float4* g = (const float4*)(x + (size_t)(rowBase + r) * 256 + ch * 64 + jb * 8);
        float4 a = g[0], b = g[1];
        uint4 p;
        p.x = pack2(a.x, a.y); p.y = pack2(a.z, a.w);
        p.z = pack2(b.x, b.y); p.w = pack2(b.z, b.w);
        *(uint4*)(void*)(xS + ch * 8192 + r * 64 + ((jb ^ (r & 7)) * 8)) = p;
    }
    __syncthreads();

    // ---- phase 1: A-fragments to registers (128 VGPRs/lane) ----
    bf16x8 af[4][8];
    #pragma unroll
    for (int ti = 0; ti < 4; ++ti) {
        int r = waveRowOff + ti * 16 + lane15;
        #pragma unroll
        for (int ks = 0; ks < 8; ++ks) {
            int off = (ks >> 1) * 8192 + r * 64 + ((((ks & 1) * 4 + quad) ^ (r & 7)) * 8);
            af[ti][ks] = *(const bf16x8*)(xS + off);
        }
    }
    __syncthreads();                      // xS reads done; LDS reusable for e bufs

    u16* bufA = (u16*)lds;                // 16 KB each, [128 c][64] swizzled
    u16* bufB = (u16*)(lds + 16384);

    // cooperative e-tile staging: all 4 waves, 4 glds16 each
    auto stage = [&](int idx, u16* dstBuf) {
        const int ctB = (idx >> 2) * CT;
        const int ch = idx & 3;
        #pragma unroll
        for (int i = 0; i < 4; ++i) {
            int u = (w * 4 + i) * 64 + l;
            int r = u >> 3;
            int sb = (u & 7) ^ (r & 7);
            glds16(ehi + (size_t)(ctB + r) * 256 + ch * 64 + sb * 8,
                   dstBuf + (w * 4 + i) * 512);
        }
    };

    float bv[16], sv[16]; int bi[16];
    #pragma unroll
    for (int i = 0; i < 16; ++i) { bv[i] = FLT_MAX; sv[i] = FLT_MAX; bi[i] = INT_MAX; }

    stage(0, bufA);
    __syncthreads();

    #pragma unroll 1
    for (int ct = 0; ct < 8; ++ct) {
        const int ctBase = ct * CT;
        f32x4 acc[4][4];
        #pragma unroll
        for (int ti = 0; ti < 4; ++ti)
            #pragma unroll
            for (int tj = 0; tj < 4; ++tj) acc[ti][tj] = (f32x4){0.f, 0.f, 0.f, 0.f};

        #pragma unroll
        for (int ch = 0; ch < 4; ++ch) {
            const int idx = ct * 4 + ch;
            u16* cur = (idx & 1) ? bufB : bufA;
            if (idx + 1 < 32) stage(idx + 1, (idx & 1) ? bufA : bufB);
            #pragma unroll
            for (int kk = 0; kk < 2; ++kk) {
                const int ks = ch * 2 + kk;
                bf16x8 bfv[4];
                #pragma unroll
                for (int tj = 0; tj < 4; ++tj) {
                    int r = waveColOff + tj * 16 + lane15;
                    bfv[tj] = *(const bf16x8*)(cur + r * 64 + (((kk * 4 + quad) ^ (r & 7)) * 8));
                }
                #pragma unroll
                for (int ti = 0; ti < 4; ++ti)
                    #pragma unroll
                    for (int tj = 0; tj < 4; ++tj)
                        acc[ti][tj] = __builtin_amdgcn_mfma_f32_16x16x32_bf16(
                            af[ti][ks], bfv[tj], acc[ti][tj], 0, 0, 0);
            }
            __syncthreads();              // staging idx+1 done; cur free next iter
        }

        // epilogue: s = ||e||^2 - 2*dot. D-layout row(M)=quad*4+reg, col(N)=lane&15
        // (proven r4-r6). Candidates ascend in c -> '<' keeps lowest index.
        #pragma unroll
        for (int tj = 0; tj < 4; ++tj) {
            int cLoc = waveColOff + tj * 16 + lane15;
            float cs = esq[ctBase + cLoc];
            int c = ctBase + cLoc;
            #pragma unroll
            for (int ti = 0; ti < 4; ++ti)
                #pragma unroll
                for (int r4 = 0; r4 < 4; ++r4) {
                    int slot = ti * 4 + r4;
                    float s = fmaf(-2.0f, acc[ti][tj][r4], cs);
                    if (s < bv[slot]) {
                        sv[slot] = bv[slot]; bv[slot] = s; bi[slot] = c;
                    } else if (s < sv[slot]) {
                        sv[slot] = s;
                    }
                }
        }
    }

    // ---- final cross-contributor top-2 merge via LDS (proven r4-r6) ----
    __syncthreads();
    float* bvA = (float*)lds;                     // [128 rows][32 contributors]
    float* svA = (float*)(lds + 16384);
    int*   biA = (int*)(lds + 32768);
    int*   idxS = (int*)(lds + 49152);            // chosen idx per row
    const int contrib = (w & 1) * 16 + lane15;
    #pragma unroll
    for (int slot = 0; slot < 16; ++slot) {
        int m = waveRowOff + (slot >> 2) * 16 + quad * 4 + (slot & 3);
        bvA[m * 32 + contrib] = bv[slot];
        svA[m * 32 + contrib] = sv[slot];
        biA[m * 32 + contrib] = bi[slot];
    }
    __syncthreads();

    if (t < ROWS_PB) {
        float bb = FLT_MAX, ss = FLT_MAX;
        int ii = INT_MAX;
        for (int k = 0; k < 32; ++k) {
            float v  = bvA[t * 32 + k];
            int   id = biA[t * 32 + k];
            float s2 = svA[t * 32 + k];
            if (v < bb || (v == bb && id < ii)) {
                ss = fminf(bb, s2);
                bb = v; ii = id;
            } else {
                ss = fminf(ss, v);
            }
        }
        idxS[t] = ii;
        out[(size_t)OUT_IDX_OFF + rowBase + t] = (float)ii;
        if (ss - bb < EPS_MARGIN) {
            int p = atomicAdd(flagCnt, 1);
            flagList[p] = rowBase + t;
        }
    }
    __syncthreads();

    // ---- fused gather: quantized out + fp64 SSE partial for this block ----
    const float4* x4 = (const float4*)x;
    const float4* e4 = (const float4*)e;
    float4* q4 = (float4*)out;
    double sse = 0.0;
    #pragma unroll 4
    for (int i = 0; i < 32; ++i) {
        int u = i * 256 + t;              // 0..8191 local float4 units
        int rloc = u >> 6;
        int c4 = u & 63;
        int idx = idxS[rloc];
        float4 qv = e4[(size_t)idx * 64 + c4];
        float4 xv = x4[(size_t)rowBase * 64 + u];
        q4[(size_t)rowBase * 64 + u] = qv;
        double dx = (double)qv.x - (double)xv.x;
        double dy = (double)qv.y - (double)xv.y;
        double dz = (double)qv.z - (double)xv.z;
        double dw = (double)qv.w - (double)xv.w;
        sse += dx * dx + dy * dy + dz * dz + dw * dw;
    }
    #pragma unroll
    for (int m = 1; m < 64; m <<= 1) sse += __shfl_xor(sse, m);
    __shared__ double wsum[4];
    if (l == 0) wsum[w] = sse;
    __syncthreads();
    if (t == 0) partials[blockIdx.x] = wsum[0] + wsum[1] + wsum[2] + wsum[3];
}

// ------- Kernel A2: flagged-row rescore + output correction -------
// Phase A: bf16 fp32 scores via q-major ehiT (coalesced, shared across RB rows)
// -> per-row shortlist within SHORTLIST_EPS of min. Phase B: numpy-emulated
// quantized score on shortlist (round-3 proven). If the winner changed,
// rewrite the quantized row + idx and atomicAdd the fp64 SSE delta.
__launch_bounds__(256)
__global__ void rescore_kernel(const float* __restrict__ x, const float* __restrict__ e,
                               const u16* __restrict__ ehiT, const float* __restrict__ esq,
                               float* __restrict__ out, const int* __restrict__ flagCnt,
                               const int* __restrict__ flagList, double* __restrict__ delta) {
    __shared__ __align__(16) float xsh[RB][DIM];
    __shared__ float Ash[RB];
    __shared__ float minsh[RB][256];
    __shared__ float thrsh[RB];
    __shared__ int scnt[RB];
    __shared__ int slist[RB][32];
    __shared__ float sres[RB][32];
    __shared__ int ncorr;
    __shared__ int corrRow[RB], corrOld[RB], corrNew[RB], corrSlot[RB];
    const int t = threadIdx.x;
    const int cnt = *flagCnt;
    const int ngroups = (cnt + RB - 1) / RB;
    float* outIdx = out + OUT_IDX_OFF;
    for (int g = blockIdx.x; g < ngroups; g += gridDim.x) {
        const int base = g * RB;
        const int nr = (cnt - base < RB) ? (cnt - base) : RB;
        __syncthreads();
        #pragma unroll
        for (int r = 0; r < RB; ++r)
            xsh[r][t] = (r < nr) ? x[(size_t)flagList[base + r] * DIM + t] : 0.0f;
        if (t < RB) scnt[t] = 0;
        if (t == 0) ncorr = 0;
        __syncthreads();
        if (t < RB) Ash[t] = np_pairwise_sumsq(xsh[t]);

        float sA[4][RB];
        #pragma unroll
        for (int j = 0; j < 4; ++j)
            #pragma unroll
            for (int r = 0; r < RB; ++r) sA[j][r] = 0.0f;

        const uint4* eT4 = (const uint4*)ehiT;
        for (int q = 0; q < 32; ++q) {
            float4 xq[RB][2];
            #pragma unroll
            for (int r = 0; r < RB; ++r) {
                xq[r][0] = ((const float4*)xsh[r])[2 * q];
                xq[r][1] = ((const float4*)xsh[r])[2 * q + 1];
            }
            #pragma unroll
            for (int j = 0; j < 4; ++j) {
                uint4 uv = eT4[(size_t)q * 1024 + j * 256 + t];
                float e0 = __uint_as_float(uv.x << 16);
                float e1 = __uint_as_float(uv.x & 0xffff0000u);
                float e2 = __uint_as_float(uv.y << 16);
                float e3 = __uint_as_float(uv.y & 0xffff0000u);
                float e4v = __uint_as_float(uv.z << 16);
                float e5 = __uint_as_float(uv.z & 0xffff0000u);
                float e6 = __uint_as_float(uv.w << 16);
                float e7 = __uint_as_float(uv.w & 0xffff0000u);
                #pragma unroll
                for (int r = 0; r < RB; ++r) {
                    float d0 = sA[j][r];
                    d0 = fmaf(e0, xq[r][0].x, d0);
                    d0 = fmaf(e1, xq[r][0].y, d0);
                    d0 = fmaf(e2, xq[r][0].z, d0);
                    d0 = fmaf(e3, xq[r][0].w, d0);
                    d0 = fmaf(e4v, xq[r][1].x, d0);
                    d0 = fmaf(e5, xq[r][1].y, d0);
                    d0 = fmaf(e6, xq[r][1].z, d0);
                    d0 = fmaf(e7, xq[r][1].w, d0);
                    sA[j][r] = d0;
                }
            }
        }
        #pragma unroll
        for (int j = 0; j < 4; ++j) {
            float cs = esq[j * 256 + t];
            #pragma unroll
            for (int r = 0; r < RB; ++r)
                sA[j][r] = fmaf(-2.0f, sA[j][r], cs);
        }
        #pragma unroll
        for (int r = 0; r < RB; ++r)
            minsh[r][t] = fminf(fminf(sA[0][r], sA[1][r]), fminf(sA[2][r], sA[3][r]));
        __syncthreads();
        for (int off = 128; off > 0; off >>= 1) {
            if (t < off) {
                #pragma unroll
                for (int r = 0; r < RB; ++r)
                    minsh[r][t] = fminf(minsh[r][t], minsh[r][t + off]);
            }
            __syncthreads();
        }
        if (t < RB) thrsh[t] = minsh[t][0] + SHORTLIST_EPS;
        __syncthreads();
        #pragma unroll
        for (int j = 0; j < 4; ++j)
            #pragma unroll
            for (int r = 0; r < RB; ++r)
                if (r < nr && sA[j][r] <= thrsh[r]) {
                    int p = atomicAdd(&scnt[r], 1);
                    if (p < 32) slist[r][p] = j * 256 + t;
                }
        __syncthreads();
        {
            int r = t >> 5, k = t & 31;
            int ns = scnt[r] < 32 ? scnt[r] : 32;
            if (r < nr && k < ns) {
                int c = slist[r][k];
                const float4* ec4 = (const float4*)(e + (size_t)c * DIM);
                const float4* xc4 = (const float4*)xsh[r];
                double dot = 0.0;
                #pragma unroll 8
                for (int d4 = 0; d4 < 64; ++d4) {
                    float4 ev = ec4[d4];
                    float4 xv = xc4[d4];
                    dot += (double)ev.x * (double)xv.x + (double)ev.y * (double)xv.y
                         + (double)ev.z * (double)xv.z + (double)ev.w * (double)xv.w;
                }
                float M = (float)dot;
                sres[r][k] = __fsub_rn(__fadd_rn(Ash[r], esq[c]), __fmul_rn(2.0f, M));
            }
        }
        __syncthreads();
        if (t < nr) {
            int ns = scnt[t] < 32 ? scnt[t] : 32;
            float bb = FLT_MAX; int ii = INT_MAX;
            for (int k = 0; k < ns; ++k) {
                float s = sres[t][k]; int c = slist[t][k];
                if (s < bb || (s == bb && c < ii)) { bb = s; ii = c; }
            }
            int row = flagList[base + t];
            int old = (int)outIdx[row];
            if (ii != old) {
                int p = atomicAdd(&ncorr, 1);
                corrRow[p] = row; corrOld[p] = old; corrNew[p] = ii; corrSlot[p] = t;
            }
        }
        __syncthreads();
        // corrections (rare): rewrite quantized row + idx, fp64 SSE delta
        for (int k = 0; k < ncorr; ++k) {
            int row = corrRow[k], io = corrOld[k], in_ = corrNew[k], sl = corrSlot[k];
            if (t < 64) {
                float4 en = ((const float4*)e)[(size_t)in_ * 64 + t];
                float4 eo = ((const float4*)e)[(size_t)io * 64 + t];
                const float* xp = xsh[sl] + t * 4;
                ((float4*)out)[(size_t)row * 64 + t] = en;
                double d = 0.0;
                double dn, dox;
                dn = (double)en.x - (double)xp[0]; dox = (double)eo.x - (double)xp[0];
                d += dn * dn - dox * dox;
                dn = (double)en.y - (double)xp[1]; dox = (double)eo.y - (double)xp[1];
                d += dn * dn - dox * dox;
                dn = (double)en.z - (double)xp[2]; dox = (double)eo.z - (double)xp[2];
                d += dn * dn - dox * dox;
                dn = (double)en.w - (double)xp[3]; dox = (double)eo.w - (double)xp[3];
                d += dn * dn - dox * dox;
                #pragma unroll
                for (int m = 1; m < 64; m <<= 1) d += __shfl_xor(d, m);
                if (t == 0) {
                    atomicAdd(delta, d);
                    outIdx[row] = (float)in_;
                }
            }
            __syncthreads();
        }
    }
}

// ---------------- Kernel C: final loss reduce ----------------
__global__ void loss_kernel(const double* __restrict__ partials,
                            const double* __restrict__ delta, float* __restrict__ out) {
    __shared__ double sh[256];
    const int t = threadIdx.x;
    sh[t] = partials[t] + partials[t + 256];
    __syncthreads();
    for (int off = 128; off > 0; off >>= 1) {
        if (t < off) sh[t] += sh[t + off];
        __syncthreads();
    }
    if (t == 0) out[OUT_LOSS_OFF] = (float)(0.25 * (sh[0] + *delta) / (double)N_ELEM);
}

extern "C" void kernel_launch(void* const* d_in, const int* in_sizes, int n_in,
                              void* d_out, int out_size, void* d_ws, size_t ws_size,
                              hipStream_t stream) {
    (void)in_sizes; (void)n_in; (void)out_size; (void)ws_size;
    const float* x = (const float*)d_in[0];
    const float* e = (const float*)d_in[1];
    float* out = (float*)d_out;
    char* ws = (char*)d_ws;
    double* partials = (double*)(ws + WS_PARTIALS);
    double* delta = (double*)(ws + WS_DELTA);
    int* flagCnt = (int*)(ws + WS_FLAGCNT);
    float* esq = (float*)(ws + WS_ESQ);
    int* flagList = (int*)(ws + WS_FLAGLIST);
    u16* ehi = (u16*)(ws + WS_EHI);
    u16* ehiT = (u16*)(ws + WS_EHIT);

    hipMemsetAsync(ws + WS_DELTA, 0, 16, stream);   // delta + flagCnt
    eprep_kernel<<<256, 256, 0, stream>>>(e, ehi, ehiT, esq);
    argmin_kernel<<<N_ROWS / ROWS_PB, 256, 0, stream>>>(x, ehi, esq, e, out,
                                                        partials, flagCnt, flagList);
    rescore_kernel<<<512, 256, 0, stream>>>(x, e, ehiT, esq, out, flagCnt,
                                            flagList, delta);
    loss_kernel<<<1, 256, 0, stream>>>(partials, delta, out);
}